// Round 17
// baseline (277.527 us; speedup 1.0000x reference)
//
#include <hip/hip_runtime.h>

typedef __bf16 bf16x8 __attribute__((ext_vector_type(8)));
typedef __bf16 bf16x4 __attribute__((ext_vector_type(4)));
typedef float f32x4 __attribute__((ext_vector_type(4)));

#define D_MODEL 1024
#define NUM_HEADS 16
#define DK 64
#define BATCH 2
#define SEQ 2048
#define M_ROWS (BATCH*SEQ)

// (1/sqrt(DK)) * log2(e): folded into Q projection so attn uses exp2(z) raw
#define QSCALE 0.18033688011112042f

#if defined(__has_builtin)
#if __has_builtin(__builtin_amdgcn_exp2f)
#define EXP2(x) __builtin_amdgcn_exp2f(x)
#endif
#endif
#ifndef EXP2
#define EXP2(x) exp2f(x)
#endif

#define ACT ((size_t)M_ROWS * D_MODEL)   // 4194304 = 2^22
#define WSZ ((size_t)D_MODEL * D_MODEL)  // 1048576 = 2^20

// 128(M)x64(N) GEMM tile, BK=64, XOR-swizzled LDS (row r's chunk j at pos
// j^(r&7)), 4 waves, acc[4][2].
// R17: cvt_all DELETED -- fp32 inputs converted in-flight during staging.
// Reg-staged 2-barrier loop (attn's proven pattern): load fp32/bf16 tile
// regs early, cvt+ds_write in the staging region, MFMA from single-buffer
// LDS (24KB -> 5-6 blocks/CU vs 3). ds_write slots identical to the old
// DMA placement, so the swizzled read side is byte-identical. The
// (__bf16)float cast matches what cvt_all produced -> numerics unchanged.
// R16 A/B: counted-vmcnt 3-deep == __syncthreads 2-phase (both ~228) ->
// barrier drain is NOT the GEMM stall at this shape; schedule levers
// exhausted, so this round removes WORK instead (the 16us cvt pass).
template <typename OutT, int MI, bool CA, bool CB>
__device__ __forceinline__ void gemm_body_rs(
    const void* __restrict__ Av, const void* __restrict__ Wv,
    const float* __restrict__ bias, OutT* __restrict__ C,
    int M, int N, int K, int m0, int n0, float scale)
{
  __shared__ __align__(16) __bf16 sA[MI*32*64];
  __shared__ __align__(16) __bf16 sB[64*64];
  const int tid  = threadIdx.x;
  const int wave = tid >> 6;
  const int lane = tid & 63;
  const int l16  = lane & 15;
  const int quad = lane >> 4;
  const int wm = (wave >> 1) * (MI * 16);
  const int wn = (wave & 1) * 32;

  const float*  A32 = (const float*)Av;
  const __bf16* A16 = (const __bf16*)Av;
  const float*  W32 = (const float*)Wv;
  const __bf16* W16 = (const __bf16*)Wv;

  f32x4 acc[MI][2] = {};

  // staging: thread's lds slot c=i*256+tid holds row c>>3, chunk pos c&7;
  // source global chunk = (c&7)^((c>>3)&7) = (tid&7)^((tid>>3)&7).
  // gsw is in ELEMENTS -> dtype-independent.
  const int gsw = (((tid & 7) ^ ((tid >> 3) & 7))) * 8;
  long aoff[MI], boff[2];
#pragma unroll
  for (int i = 0; i < MI; i++) {
    int row = (i * 256 + tid) >> 3;
    aoff[i] = (long)(m0 + row) * K + gsw;
  }
#pragma unroll
  for (int i = 0; i < 2; i++) {
    int row = (i * 256 + tid) >> 3;
    boff[i] = (long)(n0 + row) * K + gsw;
  }
  const int rsw = l16 & 7;  // read swizzle selector (= row&7 for all frags)

  const int NT = K / 64;

  // staging registers (raw loads held until the write phase so the loads
  // wait at USE, not at issue -- R10 lesson)
  float4 a0[MI], a1[MI]; uint4 aU[MI];
  float4 b0[2],  b1[2];  uint4 bU[2];

  auto loadT = [&](int kk) {
#pragma unroll
    for (int i = 0; i < MI; i++) {
      if constexpr (CA) {
        a0[i] = *(const float4*)(A32 + aoff[i] + kk);
        a1[i] = *(const float4*)(A32 + aoff[i] + kk + 4);
      } else {
        aU[i] = *(const uint4*)(A16 + aoff[i] + kk);
      }
    }
#pragma unroll
    for (int i = 0; i < 2; i++) {
      if constexpr (CB) {
        b0[i] = *(const float4*)(W32 + boff[i] + kk);
        b1[i] = *(const float4*)(W32 + boff[i] + kk + 4);
      } else {
        bU[i] = *(const uint4*)(W16 + boff[i] + kk);
      }
    }
  };

  auto writeS = [&]() {
#pragma unroll
    for (int i = 0; i < MI; i++) {
      if constexpr (CA) {
        bf16x8 w;
#pragma unroll
        for (int e = 0; e < 4; e++) {
          w[e]     = (__bf16)((&a0[i].x)[e]);
          w[4 + e] = (__bf16)((&a1[i].x)[e]);
        }
        *(bf16x8*)((char*)sA + i * 4096 + tid * 16) = w;
      } else {
        *(uint4*)((char*)sA + i * 4096 + tid * 16) = aU[i];
      }
    }
#pragma unroll
    for (int i = 0; i < 2; i++) {
      if constexpr (CB) {
        bf16x8 w;
#pragma unroll
        for (int e = 0; e < 4; e++) {
          w[e]     = (__bf16)((&b0[i].x)[e]);
          w[4 + e] = (__bf16)((&b1[i].x)[e]);
        }
        *(bf16x8*)((char*)sB + i * 4096 + tid * 16) = w;
      } else {
        *(uint4*)((char*)sB + i * 4096 + tid * 16) = bU[i];
      }
    }
  };

  loadT(0);  // prologue: tile 0 into regs

  for (int t = 0; t < NT; t++) {
    __syncthreads();   // previous tile's LDS reads done
    writeS();          // stage tile t (cvt here if fp32)
    if (t + 1 < NT) loadT((t + 1) * 64);  // issue-early; waits at next writeS
    __syncthreads();   // tile t visible

#pragma unroll
    for (int ks = 0; ks < 2; ks++) {
      bf16x8 af[MI], bf[2];
#pragma unroll
      for (int i = 0; i < MI; i++)
        af[i] = *(const bf16x8*)&sA[(wm + i * 16 + l16) * 64 + ((ks * 4 + quad) ^ rsw) * 8];
#pragma unroll
      for (int j = 0; j < 2; j++)
        bf[j] = *(const bf16x8*)&sB[(wn + j * 16 + l16) * 64 + ((ks * 4 + quad) ^ rsw) * 8];
#pragma unroll
      for (int i = 0; i < MI; i++)
#pragma unroll
        for (int j = 0; j < 2; j++)
          acc[i][j] = __builtin_amdgcn_mfma_f32_16x16x32_bf16(af[i], bf[j], acc[i][j], 0, 0, 0);
    }
  }

#pragma unroll
  for (int j = 0; j < 2; j++) {
    int col = n0 + wn + j * 16 + l16;
    float bv = bias[col];
#pragma unroll
    for (int i = 0; i < MI; i++) {
      long row0 = m0 + wm + i * 16 + quad * 4;
#pragma unroll
      for (int r = 0; r < 4; r++)
        C[(row0 + r) * N + col] = (OutT)((acc[i][j][r] + bv) * scale);
    }
  }
}

// T1 XCD-aware bijective swizzle; swz walks N-tiles fastest within an XCD
// so the A-panel stays XCD-L2-hot and each W fits XCD L2.
// Inputs are the RAW fp32 tensors (no pre-conversion pass).
__global__ __launch_bounds__(256) void gemm_qkv(
    const float* __restrict__ x_q, const float* __restrict__ x_k,
    const float* __restrict__ x_v, const float* __restrict__ Wq,
    const float* __restrict__ Wk, const float* __restrict__ Wv,
    const float* __restrict__ b0, const float* __restrict__ b1,
    const float* __restrict__ b2, __bf16* __restrict__ Cbase)
{
  int lid = blockIdx.x + (blockIdx.y << 4) + (blockIdx.z << 9);  // grid (16,32,3)
  int swz = (lid & 7) * 192 + (lid >> 3);  // 1536/8 = 192 tiles per XCD
  int x = swz & 15, y = (swz >> 4) & 31, z = swz >> 9;
  const float* A = z == 0 ? x_q : (z == 1 ? x_k : x_v);
  const float* W = z == 0 ? Wq : (z == 1 ? Wk : Wv);
  const float* bias = z == 0 ? b0 : (z == 1 ? b1 : b2);
  float scale = z == 0 ? QSCALE : 1.0f;  // fold softmax scale into Q
  __bf16* C = Cbase + (size_t)z * M_ROWS * D_MODEL;
  gemm_body_rs<__bf16, 4, true, true>(A, W, bias, C, M_ROWS, D_MODEL, D_MODEL,
                                      y * 128, x * 64, scale);
}

// A = attn output (bf16 passthrough), W = Wo (fp32, cvt in staging).
__global__ __launch_bounds__(256) void gemm_out(
    const __bf16* __restrict__ A, const float* __restrict__ W,
    const float* __restrict__ bias, float* __restrict__ C)
{
  int lid = blockIdx.x + (blockIdx.y << 4);  // grid (16,32)
  int swz = (lid & 7) * 64 + (lid >> 3);     // 512/8 = 64 tiles per XCD
  int x = swz & 15, y = swz >> 4;
  gemm_body_rs<float, 4, false, true>(A, W, bias, C, M_ROWS, D_MODEL, D_MODEL,
                                      y * 128, x * 64, 1.0f);
}

// Flash attention -- EXACT R5 kernel (verified 70.5-71.2us across 6 runs).
// Do NOT restructure: R6-R9 (32x32 arc) and R13-R14 (q-pair split) all
// regressed by cutting co-resident-block latency cover. Busy-time
// invariants (VALU ~22us, MFMA ~14us) show the kernel is latency-bound;
// 4 blocks/CU of barrier-domain diversity is the binding resource.
// R10 A/B: prefetch must stay in the staging region (issue-early; VGPR
// loads wait at USE, not at __syncthreads).
__global__ __launch_bounds__(512) void attn_kernel(
    const __bf16* __restrict__ Q, const __bf16* __restrict__ K,
    const __bf16* __restrict__ V, __bf16* __restrict__ O)
{
  constexpr int SV_LD = 136;  // 128 keys + pad

  __shared__ __align__(16) __bf16 sK[128 * 64];       // swizzled [key][d]; f32x4 scratch in epilogue
  __shared__ __align__(16) __bf16 sVt[DK * SV_LD];    // [d][pi(key)]
  __shared__ float lsbuf[8][16];

  const int tid  = threadIdx.x;
  const int wave = tid >> 6;
  const int g    = wave & 3;   // q-group (16 rows)
  const int kh   = wave >> 2;  // key half (64 keys)
  const int lane = tid & 63;
  const int l16  = lane & 15;
  const int quad = lane >> 4;

  const int bh = blockIdx.y;
  const int b  = bh >> 4, h = bh & (NUM_HEADS - 1);
  const int q0 = blockIdx.x * 64;
  const long base = (long)b * SEQ * D_MODEL + h * DK;

  // Q fragments (B operand of S^T MFMA), register-resident for the kernel
  const __bf16* qrow = Q + base + (long)(q0 + g * 16 + l16) * D_MODEL + quad * 8;
  const bf16x8 aq0 = *(const bf16x8*)(qrow);
  const bf16x8 aq1 = *(const bf16x8*)(qrow + 32);

  // K reg-staging, swizzled: slot c=i*512+tid -> row c>>3, chunk pos c&7;
  // source chunk = (tid&7)^((tid>>3)&7) (i-invariant)
  const int gsw = (((tid & 7) ^ ((tid >> 3) & 7))) * 8;
  const __bf16* kp[2];
#pragma unroll
  for (int i = 0; i < 2; i++)
    kp[i] = K + base + (long)((i * 512 + tid) >> 3) * D_MODEL + gsw;
  const int rsw = l16 & 7;

  // V staging: lane owns physical key-pair (2*lane, 2*lane+1), wave owns
  // d-group wave*8. Destination column is pi-permuted: pos bits
  // [4:3]=key[3:2], [2]=key[4], [1:0]=key[1:0]; pairs stay adjacent.
  const __bf16* vp0 = V + base + (long)(2 * lane) * D_MODEL + wave * 8;
  const int k5 = (2 * lane) & 31;
  const int pos5 = ((k5 & 12) << 1) | ((k5 & 16) >> 2) | (k5 & 3);
  const int vcol = (lane >> 4) * 16 + (pos5 >> 1);  // packed-u32 column

  // prologue prefetch: tile 0
  uint4 kr0 = *(const uint4*)(kp[0]);
  uint4 kr1 = *(const uint4*)(kp[1]);
  uint4 vr0 = *(const uint4*)(vp0);
  uint4 vr1 = *(const uint4*)(vp0 + D_MODEL);

  f32x4 lacc = {};
  f32x4 o[4] = {};  // o[dt] reg r -> partial out[q=g*16+quad*4+r][d=dt*16+l16]

  for (int t = 0; t < SEQ / 128; t++) {
    __syncthreads();  // previous tile's LDS reads done
    // write staged K (byte offset (i*512+tid)*16)
    *(uint4*)((char*)sK + tid * 16) = kr0;
    *(uint4*)((char*)sK + 8192 + tid * 16) = kr1;
    // write staged V transposed + pi-permuted, pair-packed b32 (2-way = free)
    {
      const ushort* e0 = (const ushort*)&vr0;
      const ushort* e1 = (const ushort*)&vr1;
      uint* dst = (uint*)sVt;
#pragma unroll
      for (int j = 0; j < 8; j++)
        dst[(wave * 8 + j) * (SV_LD / 2) + vcol] = (uint)e0[j] | ((uint)e1[j] << 16);
    }
    // prefetch tile t+1 into registers: issued here (early), consumed at
    // next iter's staging writes -- loads wait at USE, not at the barrier.
    if (t + 1 < SEQ / 128) {
      long adv = (long)(t + 1) * 128 * D_MODEL;
      kr0 = *(const uint4*)(kp[0] + adv);
      kr1 = *(const uint4*)(kp[1] + adv);
      vr0 = *(const uint4*)(vp0 + adv);
      vr1 = *(const uint4*)(vp0 + adv + D_MODEL);
    }
    __syncthreads();

    // Wave's half: 32-key blocks kt = kh*2 + kl. S^T for the two 16-key
    // rows of each block, softmax in-reg, af assembled (pi layout), 4 PV.
#pragma unroll
    for (int kl = 0; kl < 2; kl++) {
      const int kt = kh * 2 + kl;
      bf16x8 af;
#pragma unroll
      for (int hh = 0; hh < 2; hh++) {
        int nt = kt * 2 + hh;  // = kh*4 + kl*2 + hh
        bf16x8 b0 = *(const bf16x8*)&sK[(nt * 16 + l16) * 64 + (quad ^ rsw) * 8];
        bf16x8 b1 = *(const bf16x8*)&sK[(nt * 16 + l16) * 64 + ((4 + quad) ^ rsw) * 8];
        f32x4 z = {};
        __builtin_amdgcn_s_setprio(1);
        z = __builtin_amdgcn_mfma_f32_16x16x32_bf16(b0, aq0, z, 0, 0, 0);
        z = __builtin_amdgcn_mfma_f32_16x16x32_bf16(b1, aq1, z, 0, 0, 0);
        __builtin_amdgcn_s_setprio(0);
        f32x4 p;
#pragma unroll
        for (int r = 0; r < 4; r++) p[r] = EXP2(z[r]);  // scale pre-folded in Q
        lacc += p;
#pragma unroll
        for (int r = 0; r < 4; r++) af[hh * 4 + r] = (__bf16)p[r];
      }
      // O += P @ V : A = af (in-register, pi layout), B = V[pi(key)][d]
      __builtin_amdgcn_s_setprio(1);
#pragma unroll
      for (int dt = 0; dt < 4; dt++) {
        bf16x8 bv = *(const bf16x8*)&sVt[(dt * 16 + l16) * SV_LD + kt * 32 + quad * 8];
        o[dt] = __builtin_amdgcn_mfma_f32_16x16x32_bf16(af, bv, o[dt], 0, 0, 0);
      }
      __builtin_amdgcn_s_setprio(0);
    }
  }

  // partial lsum for q=l16 within this key half: horizontal + cross-quad
  float ls = lacc[0] + lacc[1] + lacc[2] + lacc[3];
  ls += __shfl_xor(ls, 16, 64);
  ls += __shfl_xor(ls, 32, 64);

  // combine key-halves through LDS (sK reused as f32x4 scratch [dt][g*64+lane])
  __syncthreads();  // all sK/sVt reads of the main loop done
  if (quad == 0) lsbuf[wave][l16] = ls;
  f32x4* scr = (f32x4*)sK;
  if (kh == 1) {
#pragma unroll
    for (int dt = 0; dt < 4; dt++)
      scr[dt * 256 + g * 64 + lane] = o[dt];
  }
  __syncthreads();
  if (kh == 0) {
    float lst = lsbuf[g][l16] + lsbuf[4 + g][l16];
    float rls[4];
#pragma unroll
    for (int r = 0; r < 4; r++)
      rls[r] = 1.0f / __shfl(lst, quad * 4 + r, 64);  // lane q holds lsum[q]
#pragma unroll
    for (int dt = 0; dt < 4; dt++) {
      f32x4 oo = o[dt] + scr[dt * 256 + g * 64 + lane];
#pragma unroll
      for (int r = 0; r < 4; r++) {
        int s = q0 + g * 16 + quad * 4 + r;
        int d = dt * 16 + l16;
        O[base + (long)s * D_MODEL + d] = (__bf16)(oo[r] * rls[r]);
      }
    }
  }
}

extern "C" void kernel_launch(void* const* d_in, const int* in_sizes, int n_in,
                              void* d_out, int out_size, void* d_ws, size_t ws_size,
                              hipStream_t stream) {
  const float* q  = (const float*)d_in[0];
  const float* k  = (const float*)d_in[1];
  const float* v  = (const float*)d_in[2];
  const float* Wq = (const float*)d_in[3];
  const float* bq = (const float*)d_in[4];
  const float* Wk = (const float*)d_in[5];
  const float* bk = (const float*)d_in[6];
  const float* Wv = (const float*)d_in[7];
  const float* bv = (const float*)d_in[8];
  const float* Wo = (const float*)d_in[9];
  const float* bo = (const float*)d_in[10];
  float* out = (float*)d_out;

  __bf16* wsQ  = (__bf16*)d_ws;         // Q,K,V projections contiguous (3*ACT)
  __bf16* wsAo = wsQ + 3 * ACT;         // attn output (ACT)

  dim3 blk(256);
  // no cvt pass: GEMMs read fp32 inputs directly, converting in staging

  gemm_qkv<<<dim3(D_MODEL / 64, M_ROWS / 128, 3), blk, 0, stream>>>(
      q, k, v, Wq, Wk, Wv, bq, bk, bv, wsQ);

  attn_kernel<<<dim3(SEQ / 64, BATCH * NUM_HEADS), dim3(512), 0, stream>>>(
      wsQ, wsQ + ACT, wsQ + 2 * ACT, wsAo);

  gemm_out<<<dim3(16, 32), blk, 0, stream>>>(
      wsAo, Wo, bo, out);
}

// Round 18
// 224.978 us; speedup vs baseline: 1.2336x; 1.2336x over previous
//
#include <hip/hip_runtime.h>

typedef __bf16 bf16x8 __attribute__((ext_vector_type(8)));
typedef __bf16 bf16x4 __attribute__((ext_vector_type(4)));
typedef float f32x4 __attribute__((ext_vector_type(4)));

#define D_MODEL 1024
#define NUM_HEADS 16
#define DK 64
#define BATCH 2
#define SEQ 2048
#define M_ROWS (BATCH*SEQ)

// (1/sqrt(DK)) * log2(e): folded into Q projection so attn uses exp2(z) raw
#define QSCALE 0.18033688011112042f

#if defined(__has_builtin)
#if __has_builtin(__builtin_amdgcn_exp2f)
#define EXP2(x) __builtin_amdgcn_exp2f(x)
#endif
#endif
#ifndef EXP2
#define EXP2(x) exp2f(x)
#endif

#define GLOAD_LDS16(gp, lp) __builtin_amdgcn_global_load_lds( \
    (__attribute__((address_space(1))) void*)(gp), \
    (__attribute__((address_space(3))) void*)(lp), 16, 0, 0)

#define ACT ((size_t)M_ROWS * D_MODEL)   // 4194304 = 2^22
#define WSZ ((size_t)D_MODEL * D_MODEL)  // 1048576 = 2^20

// One fused fp32->bf16 pass over all 7 tensors (dsts contiguous in ws).
// R17 lesson: fusing this into the GEMM staging REGRESSED (fp32 reg-staging
// lost the DMA pipeline; gemm_qkv 60->78us). Keep the separate pass.
__global__ __launch_bounds__(256) void cvt_all(
    const float* __restrict__ q, const float* __restrict__ k,
    const float* __restrict__ v, const float* __restrict__ wq,
    const float* __restrict__ wk, const float* __restrict__ wv,
    const float* __restrict__ wo, __bf16* __restrict__ dst)
{
  size_t e = ((size_t)blockIdx.x * 256 + threadIdx.x) * 8;
  const float* s;
  size_t off;
  if (e < 3 * ACT) {
    int t = (int)(e >> 22);
    s = t == 0 ? q : (t == 1 ? k : v);
    off = e & (ACT - 1);
  } else {
    size_t e2 = e - 3 * ACT;
    int t = (int)(e2 >> 20);
    s = t == 0 ? wq : (t == 1 ? wk : (t == 2 ? wv : wo));
    off = e2 & (WSZ - 1);
  }
  float4 a = *(const float4*)(s + off);
  float4 b = *(const float4*)(s + off + 4);
  bf16x8 o;
  o[0] = (__bf16)a.x; o[1] = (__bf16)a.y; o[2] = (__bf16)a.z; o[3] = (__bf16)a.w;
  o[4] = (__bf16)b.x; o[5] = (__bf16)b.y; o[6] = (__bf16)b.z; o[7] = (__bf16)b.w;
  *(bf16x8*)(dst + e) = o;
}

// 128(M)x64(N) GEMM tile, BK=64, XOR-swizzled LDS (row r's chunk j at pos
// j^(r&7)), 4 waves, acc[4][2]. T3 minimum 2-phase pipeline: double-buffered
// LDS; DMA for tile t+1 issued BEFORE compute of tile t; single end-of-step
// barrier drains it a full compute phase after issue. LDS 48KB.
// Lever ledger: counted-vmcnt 3-deep (R16) == this (null); split-K atomics
// (R13) -27us; 64x64 tile (R15) null; fp32-fused staging (R17) -49us.
template <typename OutT>
__device__ __forceinline__ void gemm_body(
    const __bf16* __restrict__ A, const __bf16* __restrict__ W,
    const float* __restrict__ bias, OutT* __restrict__ C,
    int M, int N, int K, int m0, int n0, float scale)
{
  __shared__ __align__(16) __bf16 sA[2][128*64];
  __shared__ __align__(16) __bf16 sB[2][64*64];
  const int tid  = threadIdx.x;
  const int wave = tid >> 6;
  const int lane = tid & 63;
  const int l16  = lane & 15;
  const int quad = lane >> 4;
  const int wm = (wave >> 1) * 64;
  const int wn = (wave & 1) * 32;

  f32x4 acc[4][2] = {};

  // staging: thread's lds slot c=i*256+tid holds row c>>3, chunk pos c&7;
  // source global chunk = (c&7)^((c>>3)&7) = (tid&7)^((tid>>3)&7)
  const int gsw = (((tid & 7) ^ ((tid >> 3) & 7))) * 8;
  long aoff[4], boff[2];
#pragma unroll
  for (int i = 0; i < 4; i++) {
    int row = (i * 256 + tid) >> 3;
    aoff[i] = (long)(m0 + row) * K + gsw;
  }
#pragma unroll
  for (int i = 0; i < 2; i++) {
    int row = (i * 256 + tid) >> 3;
    boff[i] = (long)(n0 + row) * K + gsw;
  }
  const int rsw = l16 & 7;  // read swizzle selector (= row&7 for all frags)

  const int NT = K / 64;

  // prologue: stage tile 0 into buf 0; barrier drains it
#pragma unroll
  for (int i = 0; i < 4; i++)
    GLOAD_LDS16(A + aoff[i], (char*)sA[0] + i * 4096 + tid * 16);
#pragma unroll
  for (int i = 0; i < 2; i++)
    GLOAD_LDS16(W + boff[i], (char*)sB[0] + i * 4096 + tid * 16);
  __syncthreads();

  for (int t = 0; t < NT; t++) {
    const __bf16* sAc = sA[t & 1];
    const __bf16* sBc = sB[t & 1];
    // issue next tile's DMA into the other buffer BEFORE compute: the
    // vmcnt(0) drain at this iteration's end-of-step barrier then comes a
    // full compute phase after issue. Buffer safety: the end-of-step
    // barrier of iteration t-1 guaranteed all waves finished reading
    // buf[(t+1)&1] before this overwrite.
    if (t + 1 < NT) {
      int k1 = (t + 1) * 64;
      char* sAn = (char*)sA[(t + 1) & 1];
      char* sBn = (char*)sB[(t + 1) & 1];
#pragma unroll
      for (int i = 0; i < 4; i++)
        GLOAD_LDS16(A + aoff[i] + k1, sAn + i * 4096 + tid * 16);
#pragma unroll
      for (int i = 0; i < 2; i++)
        GLOAD_LDS16(W + boff[i] + k1, sBn + i * 4096 + tid * 16);
    }
#pragma unroll
    for (int ks = 0; ks < 2; ks++) {
      bf16x8 af[4], bf[2];
#pragma unroll
      for (int i = 0; i < 4; i++)
        af[i] = *(const bf16x8*)&sAc[(wm + i * 16 + l16) * 64 + ((ks * 4 + quad) ^ rsw) * 8];
#pragma unroll
      for (int j = 0; j < 2; j++)
        bf[j] = *(const bf16x8*)&sBc[(wn + j * 16 + l16) * 64 + ((ks * 4 + quad) ^ rsw) * 8];
#pragma unroll
      for (int i = 0; i < 4; i++)
#pragma unroll
        for (int j = 0; j < 2; j++)
          acc[i][j] = __builtin_amdgcn_mfma_f32_16x16x32_bf16(af[i], bf[j], acc[i][j], 0, 0, 0);
    }
    if (t + 1 < NT) __syncthreads();  // drains DMA(t+1); next iter reads it
  }

#pragma unroll
  for (int j = 0; j < 2; j++) {
    int col = n0 + wn + j * 16 + l16;
    float bv = bias[col];
#pragma unroll
    for (int i = 0; i < 4; i++) {
      long row0 = m0 + wm + i * 16 + quad * 4;
#pragma unroll
      for (int r = 0; r < 4; r++)
        C[(row0 + r) * N + col] = (OutT)((acc[i][j][r] + bv) * scale);
    }
  }
}

// T1 XCD-aware bijective swizzle; swz walks N-tiles fastest within an XCD
// so the A-panel stays XCD-L2-hot and each W fits XCD L2.
__global__ __launch_bounds__(256) void gemm_qkv(
    const __bf16* __restrict__ Abase, const __bf16* __restrict__ Wbase,
    const float* __restrict__ b0, const float* __restrict__ b1,
    const float* __restrict__ b2, __bf16* __restrict__ Cbase)
{
  int lid = blockIdx.x + (blockIdx.y << 4) + (blockIdx.z << 9);  // grid (16,32,3)
  int swz = (lid & 7) * 192 + (lid >> 3);  // 1536/8 = 192 tiles per XCD
  int x = swz & 15, y = (swz >> 4) & 31, z = swz >> 9;
  const __bf16* A = Abase + (size_t)z * M_ROWS * D_MODEL;
  const __bf16* W = Wbase + (size_t)z * D_MODEL * D_MODEL;
  const float* bias = z == 0 ? b0 : (z == 1 ? b1 : b2);
  float scale = z == 0 ? QSCALE : 1.0f;  // fold softmax scale into Q
  __bf16* C = Cbase + (size_t)z * M_ROWS * D_MODEL;
  gemm_body<__bf16>(A, W, bias, C, M_ROWS, D_MODEL, D_MODEL,
                    y * 128, x * 64, scale);
}

__global__ __launch_bounds__(256) void gemm_out(
    const __bf16* __restrict__ A, const __bf16* __restrict__ W,
    const float* __restrict__ bias, float* __restrict__ C)
{
  int lid = blockIdx.x + (blockIdx.y << 4);  // grid (16,32)
  int swz = (lid & 7) * 64 + (lid >> 3);     // 512/8 = 64 tiles per XCD
  int x = swz & 15, y = swz >> 4;
  gemm_body<float>(A, W, bias, C, M_ROWS, D_MODEL, D_MODEL,
                   y * 128, x * 64, 1.0f);
}

// Flash attention -- EXACT R5/R12 kernel body (verified 70.5-71.2us across
// 7 runs) with ONE new element: T1 XCD-aware block remap. Default dispatch
// round-robins the (32 qblk x 32 bh) grid x-fastest, so every XCD's 4MB L2
// sees all 32 heads' K/V (16MB working set -> thrash; FETCH 69.7MB vs 24MB
// ideal). Bijective remap swz=(lid&7)*128+(lid>>3) gives each XCD a
// contiguous run of 128 blocks = 4 heads x all q-blocks -> 2MB K/V per
// XCD (L2-fits). Kernel is latency-bound, so L2-hit K/V loads shorten the
// exposed-latency term directly.
__global__ __launch_bounds__(512) void attn_kernel(
    const __bf16* __restrict__ Q, const __bf16* __restrict__ K,
    const __bf16* __restrict__ V, __bf16* __restrict__ O)
{
  constexpr int SV_LD = 136;  // 128 keys + pad

  __shared__ __align__(16) __bf16 sK[128 * 64];       // swizzled [key][d]; f32x4 scratch in epilogue
  __shared__ __align__(16) __bf16 sVt[DK * SV_LD];    // [d][pi(key)]
  __shared__ float lsbuf[8][16];

  const int tid  = threadIdx.x;
  const int wave = tid >> 6;
  const int g    = wave & 3;   // q-group (16 rows)
  const int kh   = wave >> 2;  // key half (64 keys)
  const int lane = tid & 63;
  const int l16  = lane & 15;
  const int quad = lane >> 4;

  // XCD remap: lid -> (qi, bh) such that each XCD (lid%8) owns 4 bh values
  const int lid = blockIdx.x + (blockIdx.y << 5);   // grid (32, 32)
  const int swz = (lid & 7) * 128 + (lid >> 3);     // 1024/8 = 128 per XCD
  const int qi  = swz & 31;
  const int bh  = swz >> 5;
  const int b  = bh >> 4, h = bh & (NUM_HEADS - 1);
  const int q0 = qi * 64;
  const long base = (long)b * SEQ * D_MODEL + h * DK;

  // Q fragments (B operand of S^T MFMA), register-resident for the kernel
  const __bf16* qrow = Q + base + (long)(q0 + g * 16 + l16) * D_MODEL + quad * 8;
  const bf16x8 aq0 = *(const bf16x8*)(qrow);
  const bf16x8 aq1 = *(const bf16x8*)(qrow + 32);

  // K reg-staging, swizzled: slot c=i*512+tid -> row c>>3, chunk pos c&7;
  // source chunk = (tid&7)^((tid>>3)&7) (i-invariant)
  const int gsw = (((tid & 7) ^ ((tid >> 3) & 7))) * 8;
  const __bf16* kp[2];
#pragma unroll
  for (int i = 0; i < 2; i++)
    kp[i] = K + base + (long)((i * 512 + tid) >> 3) * D_MODEL + gsw;
  const int rsw = l16 & 7;

  // V staging: lane owns physical key-pair (2*lane, 2*lane+1), wave owns
  // d-group wave*8. Destination column is pi-permuted: pos bits
  // [4:3]=key[3:2], [2]=key[4], [1:0]=key[1:0]; pairs stay adjacent.
  const __bf16* vp0 = V + base + (long)(2 * lane) * D_MODEL + wave * 8;
  const int k5 = (2 * lane) & 31;
  const int pos5 = ((k5 & 12) << 1) | ((k5 & 16) >> 2) | (k5 & 3);
  const int vcol = (lane >> 4) * 16 + (pos5 >> 1);  // packed-u32 column

  // prologue prefetch: tile 0
  uint4 kr0 = *(const uint4*)(kp[0]);
  uint4 kr1 = *(const uint4*)(kp[1]);
  uint4 vr0 = *(const uint4*)(vp0);
  uint4 vr1 = *(const uint4*)(vp0 + D_MODEL);

  f32x4 lacc = {};
  f32x4 o[4] = {};  // o[dt] reg r -> partial out[q=g*16+quad*4+r][d=dt*16+l16]

  for (int t = 0; t < SEQ / 128; t++) {
    __syncthreads();  // previous tile's LDS reads done
    // write staged K (byte offset (i*512+tid)*16)
    *(uint4*)((char*)sK + tid * 16) = kr0;
    *(uint4*)((char*)sK + 8192 + tid * 16) = kr1;
    // write staged V transposed + pi-permuted, pair-packed b32 (2-way = free)
    {
      const ushort* e0 = (const ushort*)&vr0;
      const ushort* e1 = (const ushort*)&vr1;
      uint* dst = (uint*)sVt;
#pragma unroll
      for (int j = 0; j < 8; j++)
        dst[(wave * 8 + j) * (SV_LD / 2) + vcol] = (uint)e0[j] | ((uint)e1[j] << 16);
    }
    // prefetch tile t+1 into registers: issued here (early), consumed at
    // next iter's staging writes -- loads wait at USE, not at the barrier.
    if (t + 1 < SEQ / 128) {
      long adv = (long)(t + 1) * 128 * D_MODEL;
      kr0 = *(const uint4*)(kp[0] + adv);
      kr1 = *(const uint4*)(kp[1] + adv);
      vr0 = *(const uint4*)(vp0 + adv);
      vr1 = *(const uint4*)(vp0 + adv + D_MODEL);
    }
    __syncthreads();

    // Wave's half: 32-key blocks kt = kh*2 + kl. S^T for the two 16-key
    // rows of each block, softmax in-reg, af assembled (pi layout), 4 PV.
#pragma unroll
    for (int kl = 0; kl < 2; kl++) {
      const int kt = kh * 2 + kl;
      bf16x8 af;
#pragma unroll
      for (int hh = 0; hh < 2; hh++) {
        int nt = kt * 2 + hh;  // = kh*4 + kl*2 + hh
        bf16x8 b0 = *(const bf16x8*)&sK[(nt * 16 + l16) * 64 + (quad ^ rsw) * 8];
        bf16x8 b1 = *(const bf16x8*)&sK[(nt * 16 + l16) * 64 + ((4 + quad) ^ rsw) * 8];
        f32x4 z = {};
        __builtin_amdgcn_s_setprio(1);
        z = __builtin_amdgcn_mfma_f32_16x16x32_bf16(b0, aq0, z, 0, 0, 0);
        z = __builtin_amdgcn_mfma_f32_16x16x32_bf16(b1, aq1, z, 0, 0, 0);
        __builtin_amdgcn_s_setprio(0);
        f32x4 p;
#pragma unroll
        for (int r = 0; r < 4; r++) p[r] = EXP2(z[r]);  // scale pre-folded in Q
        lacc += p;
#pragma unroll
        for (int r = 0; r < 4; r++) af[hh * 4 + r] = (__bf16)p[r];
      }
      // O += P @ V : A = af (in-register, pi layout), B = V[pi(key)][d]
      __builtin_amdgcn_s_setprio(1);
#pragma unroll
      for (int dt = 0; dt < 4; dt++) {
        bf16x8 bv = *(const bf16x8*)&sVt[(dt * 16 + l16) * SV_LD + kt * 32 + quad * 8];
        o[dt] = __builtin_amdgcn_mfma_f32_16x16x32_bf16(af, bv, o[dt], 0, 0, 0);
      }
      __builtin_amdgcn_s_setprio(0);
    }
  }

  // partial lsum for q=l16 within this key half: horizontal + cross-quad
  float ls = lacc[0] + lacc[1] + lacc[2] + lacc[3];
  ls += __shfl_xor(ls, 16, 64);
  ls += __shfl_xor(ls, 32, 64);

  // combine key-halves through LDS (sK reused as f32x4 scratch [dt][g*64+lane])
  __syncthreads();  // all sK/sVt reads of the main loop done
  if (quad == 0) lsbuf[wave][l16] = ls;
  f32x4* scr = (f32x4*)sK;
  if (kh == 1) {
#pragma unroll
    for (int dt = 0; dt < 4; dt++)
      scr[dt * 256 + g * 64 + lane] = o[dt];
  }
  __syncthreads();
  if (kh == 0) {
    float lst = lsbuf[g][l16] + lsbuf[4 + g][l16];
    float rls[4];
#pragma unroll
    for (int r = 0; r < 4; r++)
      rls[r] = 1.0f / __shfl(lst, quad * 4 + r, 64);  // lane q holds lsum[q]
#pragma unroll
    for (int dt = 0; dt < 4; dt++) {
      f32x4 oo = o[dt] + scr[dt * 256 + g * 64 + lane];
#pragma unroll
      for (int r = 0; r < 4; r++) {
        int s = q0 + g * 16 + quad * 4 + r;
        int d = dt * 16 + l16;
        O[base + (long)s * D_MODEL + d] = (__bf16)(oo[r] * rls[r]);
      }
    }
  }
}

extern "C" void kernel_launch(void* const* d_in, const int* in_sizes, int n_in,
                              void* d_out, int out_size, void* d_ws, size_t ws_size,
                              hipStream_t stream) {
  const float* q  = (const float*)d_in[0];
  const float* k  = (const float*)d_in[1];
  const float* v  = (const float*)d_in[2];
  const float* Wq = (const float*)d_in[3];
  const float* bq = (const float*)d_in[4];
  const float* Wk = (const float*)d_in[5];
  const float* bk = (const float*)d_in[6];
  const float* Wv = (const float*)d_in[7];
  const float* bv = (const float*)d_in[8];
  const float* Wo = (const float*)d_in[9];
  const float* bo = (const float*)d_in[10];
  float* out = (float*)d_out;

  __bf16* qc  = (__bf16*)d_ws;          // qc,kc,vc contiguous
  __bf16* Wqc = qc + 3 * ACT;           // Wq,Wk,Wv,Wo contiguous
  __bf16* wsQ = Wqc + 4 * WSZ;          // Q,K,V projections contiguous
  __bf16* wsAo = qc;                    // attn out reuses qc

  dim3 blk(256);
  // one fused cvt pass: 3*ACT + 4*WSZ = 2^24 elems, 8/thread
  cvt_all<<<dim3((3 * ACT + 4 * WSZ) / 2048), blk, 0, stream>>>(
      q, k, v, Wq, Wk, Wv, Wo, qc);

  gemm_qkv<<<dim3(D_MODEL / 64, M_ROWS / 128, 3), blk, 0, stream>>>(
      qc, Wqc, bq, bk, bv, wsQ);

  attn_kernel<<<dim3(SEQ / 64, BATCH * NUM_HEADS), dim3(512), 0, stream>>>(
      wsQ, wsQ + ACT, wsQ + 2 * ACT, wsAo);

  gemm_out<<<dim3(16, 32), blk, 0, stream>>>(
      wsAo, Wqc + 3 * WSZ, bo, out);
}